// Round 10
// baseline (382.417 us; speedup 1.0000x reference)
//
#include <hip/hip_runtime.h>
#include <cstdint>
#include <cstdlib>
#include <cstring>
#include <vector>

#define RW_VOCAB 512
#define RW_T 64
#define RW_NIN 2048
#define RW_NBIAS 2
#define RW_BATCH 512
#define RW_NLAYERS 6
#define RW_VBLD 4096
#define SLABSTRIDE (512 * 512)  // fp32 elems per split-K slab

typedef __attribute__((ext_vector_type(8))) short short8;  // bf16x8 frag
typedef __attribute__((ext_vector_type(4))) float f32x4;
typedef uint32_t u32;

// ---------------------------------------------------------------------------
// Host-side replication of np.random.RandomState(0) graph construction.
// (verified passing: rounds 3, 5, 6; absmax <= 9.8e-4.)
// ---------------------------------------------------------------------------
namespace {

struct MT19937 {
  uint32_t mt[624];
  int mti;
  void seed(uint32_t s) {
    for (int i = 0; i < 624; ++i) {
      mt[i] = s;
      s = 1812433253u * (s ^ (s >> 30)) + (uint32_t)i + 1u;
    }
    mti = 624;
  }
  inline uint32_t next() {
    if (mti >= 624) {
      for (int i = 0; i < 624; ++i) {
        uint32_t y = (mt[i] & 0x80000000u) | (mt[(i + 1) % 624] & 0x7fffffffu);
        mt[i] = mt[(i + 397) % 624] ^ (y >> 1) ^ ((y & 1u) ? 2567483615u : 0u);
      }
      mti = 0;
    }
    uint32_t y = mt[mti++];
    y ^= y >> 11;
    y ^= (y << 7) & 2636928640u;
    y ^= (y << 15) & 4022730752u;
    y ^= y >> 18;
    return y;
  }
  inline double rnd() {
    uint32_t a = next() >> 5, b = next() >> 6;
    return ((double)a * 67108864.0 + (double)b) / 9007199254740992.0;
  }
};

const int LAYER_SIZES[RW_NLAYERS] = {288, 288, 288, 287, 287, 512};
const int LAYER_START[RW_NLAYERS] = {2050, 2338, 2626, 2914, 3201, 3488};
const int LAYER_NPAD[RW_NLAYERS] = {288, 288, 288, 288, 288, 512};
const int LAYER_NT[RW_NLAYERS] = {9, 9, 9, 9, 9, 16};
const int LAYER_SK[RW_NLAYERS] = {7, 7, 7, 7, 7, 4};

struct GArgsH {
  int p0[RW_NLAYERS], ep[RW_NLAYERS], er[RW_NLAYERS], w0[RW_NLAYERS];
  int kpad[RW_NLAYERS];
  unsigned wofs[RW_NLAYERS];
};

struct HostGraph {
  int Epad;
  GArgsH ga;
  unsigned wdt_elems;
  uint32_t* h_pack;  // pinned: (dst_local<<12)|src_global
};

HostGraph* build_host_graph() {
  auto* G = new HostGraph();
  MT19937 mt;
  mt.seed(0);
  std::vector<uint32_t> pack;
  pack.reserve(180000);
  int start = RW_NIN + RW_NBIAS;  // 2050
  int wcum = 0;
  for (int li = 0; li < RW_NLAYERS; ++li) {
    const int size = LAYER_SIZES[li];
    G->ga.p0[li] = (int)pack.size();
    G->ga.w0[li] = wcum;
    int cnt = 0;
    for (int u = 0; u < start; ++u) {  // src-major == numpy nonzero order
      for (int v = 0; v < size; ++v) {
        if (mt.rnd() < 0.03) {
          pack.push_back(((uint32_t)v << 12) | (uint32_t)u);
          ++cnt;
        }
      }
    }
    G->ga.er[li] = cnt;
    wcum += cnt;
    while (pack.size() & 3u) pack.push_back(0u);
    G->ga.ep[li] = (int)pack.size() - G->ga.p0[li];
    start += size;
  }
  G->Epad = (int)pack.size();
  unsigned ofs = 0;
  for (int li = 0; li < RW_NLAYERS; ++li) {
    G->ga.kpad[li] = ((LAYER_START[li] + 63) / 64) * 64;
    G->ga.wofs[li] = ofs;
    ofs += (unsigned)LAYER_NPAD[li] * (unsigned)G->ga.kpad[li];
  }
  G->wdt_elems = ofs;
  const size_t bytes = (size_t)G->Epad * 4;
  if (hipHostMalloc((void**)&G->h_pack, bytes) != hipSuccess)
    G->h_pack = (uint32_t*)malloc(bytes);
  memcpy(G->h_pack, pack.data(), bytes);
  return G;
}

}  // namespace

struct GArgs {
  int p0[RW_NLAYERS], ep[RW_NLAYERS], er[RW_NLAYERS], w0[RW_NLAYERS];
  int kpad[RW_NLAYERS];
  unsigned wofs[RW_NLAYERS];
};

__device__ __forceinline__ unsigned short f2bf(float f) {
  unsigned u = __builtin_bit_cast(unsigned, f);
  return (unsigned short)((u + 0x7fffu + ((u >> 16) & 1u)) >> 16);  // RNE
}

// async global->LDS, 16B per lane; LDS dst = wave-uniform base + lane*16
__device__ __forceinline__ void gll16(const void* g, void* l) {
  __builtin_amdgcn_global_load_lds(
      (const __attribute__((address_space(1))) u32*)g,
      (__attribute__((address_space(3))) u32*)l, 16, 0, 0);
}

// ---------------------------------------------------------------------------
// init: zero dense W^T (uint4), build Vb (bf16 emb+bias+zero tail), zero cnts
// ---------------------------------------------------------------------------
__global__ __launch_bounds__(256) void rwnn_init(
    uint4* __restrict__ wdt4, int n4, uint4* __restrict__ vb4,
    const int* __restrict__ ids, const float* __restrict__ tok,
    const float* __restrict__ pos, int* __restrict__ cnt) {
  const int gt = blockIdx.x * 256 + threadIdx.x;
  const int gs = gridDim.x * 256;
  const uint4 z = {0u, 0u, 0u, 0u};
  for (int i = gt; i < n4; i += gs) wdt4[i] = z;
  for (int i = gt; i < RW_BATCH * (RW_VBLD / 8); i += gs) {
    const int b = i >> 9, j = i & 511;
    const int c0 = j * 8;
    uint4 val = z;
    if (c0 + 8 <= RW_NIN) {
      const int id = ids[b * RW_T + (c0 >> 5)];
      const float4 t0 = *(const float4*)(tok + id * 32 + (c0 & 31));
      const float4 t1 = *(const float4*)(tok + id * 32 + (c0 & 31) + 4);
      const float4 p0 = *(const float4*)(pos + c0);
      const float4 p1 = *(const float4*)(pos + c0 + 4);
      val.x = (u32)f2bf(t0.x + p0.x) | ((u32)f2bf(t0.y + p0.y) << 16);
      val.y = (u32)f2bf(t0.z + p0.z) | ((u32)f2bf(t0.w + p0.w) << 16);
      val.z = (u32)f2bf(t1.x + p1.x) | ((u32)f2bf(t1.y + p1.y) << 16);
      val.w = (u32)f2bf(t1.z + p1.z) | ((u32)f2bf(t1.w + p1.w) << 16);
    } else if (c0 == RW_NIN) {
      val.x = 0x3f803f80u;  // two bias nodes = bf16 1.0
    }
    vb4[(size_t)b * (RW_VBLD / 8) + j] = val;
  }
  if (gt < RW_NLAYERS * 64) cnt[gt] = 0;
}

// scatter sparse weights into dense bf16 W^T[n][k]
__global__ __launch_bounds__(256) void rwnn_scatter(
    const uint32_t* __restrict__ pack, const float* __restrict__ w,
    unsigned short* __restrict__ wdt, GArgs ga, int Epad) {
  const int i = blockIdx.x * 256 + threadIdx.x;
  if (i >= Epad) return;
  int l = 0;
#pragma unroll
  for (int k = 1; k < RW_NLAYERS; ++k)
    if (i >= ga.p0[k]) l = k;
  const int kk = i - ga.p0[l];
  if (kk >= ga.er[l]) return;
  const uint32_t pk = pack[i];
  const unsigned u = pk & 4095u, v = pk >> 12;
  wdt[ga.wofs[l] + (size_t)v * (unsigned)ga.kpad[l] + u] =
      f2bf(w[ga.w0[l] + kk]);
}

// ---------------------------------------------------------------------------
// GEMM layer: slab[sk] = Vb[512,K] * W^T[Npad,K]^T partials; last split-K
// block per (mt,nt) tile reduces slabs, applies tanh, writes Vb (or out).
// 2-phase double-buffered global_load_lds staging; chunk-XOR LDS swizzle.
// ---------------------------------------------------------------------------
struct GemmP {
  int kpad, ck, SK, nsize, vstart, last, cntofs;
  unsigned wofs;
};

__global__ __launch_bounds__(256) void rwnn_gemm(
    const unsigned short* __restrict__ Vb,
    const unsigned short* __restrict__ wdt, float* __restrict__ slab,
    int* __restrict__ cnt, unsigned short* __restrict__ VbW,
    float* __restrict__ out, GemmP P) {
  __shared__ unsigned short As[2][128 * 32];  // [buf][row*32 + col] bf16
  __shared__ unsigned short Bs[2][32 * 32];
  __shared__ int fin;
  const unsigned short* Bt = wdt + P.wofs;
  const int tid = threadIdx.x;
  const int wave = tid >> 6, lane = tid & 63;
  const int mt = blockIdx.x, nt = blockIdx.y, sk = blockIdx.z;
  const int k0 = sk * P.ck;
  const int k1 = min(k0 + P.ck, P.kpad);
  const int nit = (k1 > k0) ? ((k1 - k0 + 31) >> 5) : 0;

  const int srow = tid >> 2;   // staging row (A: within 64-row half)
  const int schunk = tid & 3;  // staging 16B chunk within 64B row

  f32x4 acc[2][2] = {};

#define STAGE(bf, kk)                                                        \
  do {                                                                       \
    _Pragma("unroll") for (int j = 0; j < 2; ++j) {                          \
      const int row_ = j * 64 + srow;                                        \
      const int gc_ = schunk ^ (row_ & 3);                                   \
      gll16(Vb + (size_t)(mt * 128 + row_) * RW_VBLD + (kk) + gc_ * 8,       \
            (char*)(&As[bf][0]) + j * 4096 + wave * 1024);                   \
    }                                                                        \
    if (wave < 2) {                                                          \
      const int gc_ = schunk ^ (srow & 3);                                   \
      gll16(Bt + (size_t)(nt * 32 + srow) * P.kpad + (kk) + gc_ * 8,         \
            (char*)(&Bs[bf][0]) + wave * 1024);                              \
    }                                                                        \
  } while (0)

  if (nit > 0) STAGE(0, k0);
  __syncthreads();

  const int lr = lane & 15, gc4 = lane >> 4;
  const int ra0 = wave * 32 + lr;
  const int oa0 = ra0 * 64 + ((gc4 ^ (ra0 & 3)) << 4);
  const int oa1 = oa0 + 16 * 64;  // (ra0+16)&3 == ra0&3
  const int ob0 = lr * 64 + ((gc4 ^ (lr & 3)) << 4);
  const int ob1 = ob0 + 16 * 64;

  for (int t = 0; t < nit; ++t) {
    const int bf = t & 1;
    if (t + 1 < nit) STAGE(bf ^ 1, k0 + (t + 1) * 32);  // prefetch next
    const char* a = (const char*)&As[bf][0];
    const char* bb = (const char*)&Bs[bf][0];
    const short8 a0 = *(const short8*)(a + oa0);
    const short8 a1 = *(const short8*)(a + oa1);
    const short8 b0 = *(const short8*)(bb + ob0);
    const short8 b1 = *(const short8*)(bb + ob1);
    acc[0][0] = __builtin_amdgcn_mfma_f32_16x16x32_bf16(a0, b0, acc[0][0], 0, 0, 0);
    acc[0][1] = __builtin_amdgcn_mfma_f32_16x16x32_bf16(a0, b1, acc[0][1], 0, 0, 0);
    acc[1][0] = __builtin_amdgcn_mfma_f32_16x16x32_bf16(a1, b0, acc[1][0], 0, 0, 0);
    acc[1][1] = __builtin_amdgcn_mfma_f32_16x16x32_bf16(a1, b1, acc[1][1], 0, 0, 0);
    __syncthreads();  // drains prefetch vmcnt; buffers swap safely
  }
#undef STAGE

  // store split-K partial (plain coalesced stores, no atomics)
  {
    float* sl = slab + (size_t)sk * SLABSTRIDE;
    const int lq = lane >> 4;
#pragma unroll
    for (int ms = 0; ms < 2; ++ms)
#pragma unroll
      for (int ns = 0; ns < 2; ++ns)
#pragma unroll
        for (int r = 0; r < 4; ++r) {
          const int grow = mt * 128 + wave * 32 + ms * 16 + lq * 4 + r;
          const int gcol = nt * 32 + ns * 16 + lr;
          sl[(size_t)grow * 512 + gcol] = acc[ms][ns][r];
        }
  }
  __syncthreads();  // all lanes' stores vmcnt-drained (in L2)
  if (tid == 0) {
    __threadfence();  // release: writeback to device-coherent point
    fin = (atomicAdd(cnt + P.cntofs + mt * 16 + nt, 1) == P.SK - 1) ? 1 : 0;
  }
  __syncthreads();
  if (fin) {          // last-arriving block finishes the (mt,nt) tile
    __threadfence();  // acquire: invalidate stale L1/L2
    const int c = tid & 31;
    const int gcol = nt * 32 + c;
    const bool wr = P.last ? true : (gcol < P.nsize);
    for (int rr = tid >> 5; rr < 128; rr += 8) {
      const int grow = mt * 128 + rr;
      float s = 0.f;
      for (int q = 0; q < P.SK; ++q)
        s += slab[(size_t)q * SLABSTRIDE + (size_t)grow * 512 + gcol];
      if (P.last)
        out[(size_t)grow * 512 + gcol] = s;
      else if (wr)
        VbW[(size_t)grow * RW_VBLD + P.vstart + gcol] = f2bf(tanhf(s));
    }
  }
}

// ---------------------------------------------------------------------------
// Fallback (verified round-5 path) if ws_size too small for the dense plan
// ---------------------------------------------------------------------------
__global__ __launch_bounds__(256) void rwnn_build_w(const float* __restrict__ w,
                                                    float* __restrict__ wpad,
                                                    GArgs ga, int Epad) {
  const int i = blockIdx.x * 256 + threadIdx.x;
  if (i >= Epad) return;
  int l = 0;
#pragma unroll
  for (int k = 1; k < RW_NLAYERS; ++k)
    if (i >= ga.p0[k]) l = k;
  const int kk = i - ga.p0[l];
  wpad[i] = (kk < ga.er[l]) ? w[ga.w0[l] + kk] : 0.0f;
}

__global__ __launch_bounds__(512) void rwnn_fwd_sparse(
    const int* __restrict__ ids, const float* __restrict__ tok,
    const float* __restrict__ pos, const uint32_t* __restrict__ pack,
    const float* __restrict__ wpad, float* __restrict__ out, GArgs ga) {
  __shared__ float vals[4000];
  const int b = blockIdx.x;
  const int tid = threadIdx.x;
  for (int i = tid; i < RW_NIN; i += 512) {
    const int t = i >> 5, d = i & 31;
    vals[i] = tok[(ids[b * RW_T + t] << 5) + d] + pos[i];
  }
  if (tid < RW_NBIAS) vals[RW_NIN + tid] = 1.0f;
  const int sizes[RW_NLAYERS] = {288, 288, 288, 287, 287, 512};
  int nb = RW_NIN + RW_NBIAS;
  for (int li = 0; li < RW_NLAYERS; ++li) {
    const int size = sizes[li];
    __syncthreads();
    for (int v = tid; v < size; v += 512) vals[nb + v] = 0.0f;
    __syncthreads();
    const int p0 = ga.p0[li], ng = ga.ep[li] >> 2;
    for (int g = tid; g < ng; g += 512) {
      const int e = p0 + (g << 2);
      const uint4 pk = *reinterpret_cast<const uint4*>(pack + e);
      const float4 wv = *reinterpret_cast<const float4*>(wpad + e);
      atomicAdd(&vals[nb + (pk.x >> 12)], vals[pk.x & 4095u] * wv.x);
      atomicAdd(&vals[nb + (pk.y >> 12)], vals[pk.y & 4095u] * wv.y);
      atomicAdd(&vals[nb + (pk.z >> 12)], vals[pk.z & 4095u] * wv.z);
      atomicAdd(&vals[nb + (pk.w >> 12)], vals[pk.w & 4095u] * wv.w);
    }
    __syncthreads();
    if (li == RW_NLAYERS - 1) {
      for (int v = tid; v < RW_VOCAB; v += 512)
        out[b * RW_VOCAB + v] = vals[nb + v];
    } else {
      for (int v = tid; v < size; v += 512) vals[nb + v] = tanhf(vals[nb + v]);
    }
    nb += size;
  }
}

// ---------------------------------------------------------------------------
extern "C" void kernel_launch(void* const* d_in, const int* in_sizes, int n_in,
                              void* d_out, int out_size, void* d_ws,
                              size_t ws_size, hipStream_t stream) {
  static HostGraph* G = build_host_graph();
  const int Epad = G->Epad;

  const int* ids = (const int*)d_in[0];
  const float* tok = (const float*)d_in[1];
  const float* pos = (const float*)d_in[2];
  const float* w = (const float*)d_in[3];
  float* out = (float*)d_out;

  GArgs ga;
  memcpy(&ga, &G->ga, sizeof(GArgs));

  char* ws = (char*)d_ws;
  const size_t packB = ((size_t)Epad * 4 + 255) & ~(size_t)255;
  const size_t wdtB = ((size_t)G->wdt_elems * 2 + 255) & ~(size_t)255;
  const size_t vbB = (size_t)RW_BATCH * RW_VBLD * 2;          // 4 MB
  const size_t slabB = (size_t)7 * SLABSTRIDE * 4;            // 7 MB
  const size_t cntB = RW_NLAYERS * 64 * 4;
  const size_t need = packB + wdtB + vbB + slabB + cntB;

  uint32_t* d_pack = (uint32_t*)ws;
  hipMemcpyAsync(d_pack, G->h_pack, (size_t)Epad * 4, hipMemcpyHostToDevice,
                 stream);

  if (ws_size < need) {  // fallback: verified sparse path
    float* d_wpad = (float*)(ws + packB);
    rwnn_build_w<<<(Epad + 255) / 256, 256, 0, stream>>>(w, d_wpad, ga, Epad);
    rwnn_fwd_sparse<<<RW_BATCH, 512, 0, stream>>>(ids, tok, pos, d_pack,
                                                  d_wpad, out, ga);
    return;
  }

  unsigned short* d_wdt = (unsigned short*)(ws + packB);
  unsigned short* d_vb = (unsigned short*)(ws + packB + wdtB);
  float* d_slab = (float*)(ws + packB + wdtB + vbB);
  int* d_cnt = (int*)(ws + packB + wdtB + vbB + slabB);

  rwnn_init<<<1024, 256, 0, stream>>>((uint4*)d_wdt, (int)(G->wdt_elems / 8),
                                      (uint4*)d_vb, ids, tok, pos, d_cnt);
  rwnn_scatter<<<(Epad + 255) / 256, 256, 0, stream>>>(d_pack, w, d_wdt, ga,
                                                       Epad);
  for (int l = 0; l < RW_NLAYERS; ++l) {
    GemmP P;
    P.kpad = ga.kpad[l];
    P.SK = LAYER_SK[l];
    P.ck = ((P.kpad + P.SK - 1) / P.SK + 31) & ~31;
    P.nsize = LAYER_SIZES[l];
    P.vstart = LAYER_START[l];
    P.last = (l == RW_NLAYERS - 1) ? 1 : 0;
    P.cntofs = l * 64;
    P.wofs = ga.wofs[l];
    rwnn_gemm<<<dim3(4, LAYER_NT[l], P.SK), 256, 0, stream>>>(
        d_vb, d_wdt, d_slab, d_cnt, d_vb, out, P);
  }
}

// Round 12
// 155.848 us; speedup vs baseline: 2.4538x; 2.4538x over previous
//
#include <hip/hip_runtime.h>
#include <cstdint>
#include <cstdlib>
#include <cstring>
#include <vector>

#define RW_VOCAB 512
#define RW_T 64
#define RW_NIN 2048
#define RW_NBIAS 2
#define RW_BATCH 512
#define RW_NLAYERS 6
#define RW_VBLD 4096

typedef __attribute__((ext_vector_type(8))) short short8;  // bf16x8 frag
typedef __attribute__((ext_vector_type(4))) float f32x4;
typedef uint32_t u32;

// ---------------------------------------------------------------------------
// Host-side replication of np.random.RandomState(0) graph construction.
// (verified passing: rounds 3, 5, 6, 10; absmax <= 9.8e-4.)
// ---------------------------------------------------------------------------
namespace {

struct MT19937 {
  uint32_t mt[624];
  int mti;
  void seed(uint32_t s) {
    for (int i = 0; i < 624; ++i) {
      mt[i] = s;
      s = 1812433253u * (s ^ (s >> 30)) + (uint32_t)i + 1u;
    }
    mti = 624;
  }
  inline uint32_t next() {
    if (mti >= 624) {
      for (int i = 0; i < 624; ++i) {
        uint32_t y = (mt[i] & 0x80000000u) | (mt[(i + 1) % 624] & 0x7fffffffu);
        mt[i] = mt[(i + 397) % 624] ^ (y >> 1) ^ ((y & 1u) ? 2567483615u : 0u);
      }
      mti = 0;
    }
    uint32_t y = mt[mti++];
    y ^= y >> 11;
    y ^= (y << 7) & 2636928640u;
    y ^= (y << 15) & 4022730752u;
    y ^= y >> 18;
    return y;
  }
  inline double rnd() {
    uint32_t a = next() >> 5, b = next() >> 6;
    return ((double)a * 67108864.0 + (double)b) / 9007199254740992.0;
  }
};

const int LAYER_SIZES[RW_NLAYERS] = {288, 288, 288, 287, 287, 512};
const int LAYER_START[RW_NLAYERS] = {2050, 2338, 2626, 2914, 3201, 3488};
const int LAYER_NPAD[RW_NLAYERS] = {288, 288, 288, 288, 288, 512};
const int LAYER_NT[RW_NLAYERS] = {9, 9, 9, 9, 9, 16};
const int LAYER_SK[RW_NLAYERS] = {7, 7, 7, 7, 7, 4};

struct GArgsH {
  int p0[RW_NLAYERS], ep[RW_NLAYERS], er[RW_NLAYERS], w0[RW_NLAYERS];
  int kpad[RW_NLAYERS];
  unsigned wofs[RW_NLAYERS];
};

struct HostGraph {
  int Epad;
  GArgsH ga;
  unsigned wdt_elems;
  uint32_t* h_pack;  // pinned: (dst_local<<12)|src_global
};

HostGraph* build_host_graph() {
  auto* G = new HostGraph();
  MT19937 mt;
  mt.seed(0);
  std::vector<uint32_t> pack;
  pack.reserve(180000);
  int start = RW_NIN + RW_NBIAS;  // 2050
  int wcum = 0;
  for (int li = 0; li < RW_NLAYERS; ++li) {
    const int size = LAYER_SIZES[li];
    G->ga.p0[li] = (int)pack.size();
    G->ga.w0[li] = wcum;
    int cnt = 0;
    for (int u = 0; u < start; ++u) {  // src-major == numpy nonzero order
      for (int v = 0; v < size; ++v) {
        if (mt.rnd() < 0.03) {
          pack.push_back(((uint32_t)v << 12) | (uint32_t)u);
          ++cnt;
        }
      }
    }
    G->ga.er[li] = cnt;
    wcum += cnt;
    while (pack.size() & 3u) pack.push_back(0u);
    G->ga.ep[li] = (int)pack.size() - G->ga.p0[li];
    start += size;
  }
  G->Epad = (int)pack.size();
  unsigned ofs = 0;
  for (int li = 0; li < RW_NLAYERS; ++li) {
    G->ga.kpad[li] = ((LAYER_START[li] + 63) / 64) * 64;
    G->ga.wofs[li] = ofs;
    ofs += (unsigned)LAYER_NPAD[li] * (unsigned)G->ga.kpad[li];
  }
  G->wdt_elems = ofs;
  const size_t bytes = (size_t)G->Epad * 4;
  if (hipHostMalloc((void**)&G->h_pack, bytes) != hipSuccess)
    G->h_pack = (uint32_t*)malloc(bytes);
  memcpy(G->h_pack, pack.data(), bytes);
  return G;
}

}  // namespace

struct GArgs {
  int p0[RW_NLAYERS], ep[RW_NLAYERS], er[RW_NLAYERS], w0[RW_NLAYERS];
  int kpad[RW_NLAYERS];
  unsigned wofs[RW_NLAYERS];
};

__device__ __forceinline__ unsigned short f2bf(float f) {
  unsigned u = __builtin_bit_cast(unsigned, f);
  return (unsigned short)((u + 0x7fffu + ((u >> 16) & 1u)) >> 16);  // RNE
}

// ---------------------------------------------------------------------------
// init: zero dense W^T, zero pre, build Vb (bf16 emb + bias + zero tail)
// ---------------------------------------------------------------------------
__global__ __launch_bounds__(256) void rwnn_init(
    uint4* __restrict__ wdt4, int n4, uint4* __restrict__ pre4,
    uint4* __restrict__ vb4, const int* __restrict__ ids,
    const float* __restrict__ tok, const float* __restrict__ pos) {
  const int gt = blockIdx.x * 256 + threadIdx.x;
  const int gs = gridDim.x * 256;
  const uint4 z = {0u, 0u, 0u, 0u};
  for (int i = gt; i < n4; i += gs) wdt4[i] = z;
  for (int i = gt; i < RW_BATCH * 512 / 4; i += gs) pre4[i] = z;
  for (int i = gt; i < RW_BATCH * (RW_VBLD / 8); i += gs) {
    const int b = i >> 9, j = i & 511;
    const int c0 = j * 8;
    uint4 val = z;
    if (c0 + 8 <= RW_NIN) {
      const int id = ids[b * RW_T + (c0 >> 5)];
      const float4 t0 = *(const float4*)(tok + id * 32 + (c0 & 31));
      const float4 t1 = *(const float4*)(tok + id * 32 + (c0 & 31) + 4);
      const float4 p0 = *(const float4*)(pos + c0);
      const float4 p1 = *(const float4*)(pos + c0 + 4);
      val.x = (u32)f2bf(t0.x + p0.x) | ((u32)f2bf(t0.y + p0.y) << 16);
      val.y = (u32)f2bf(t0.z + p0.z) | ((u32)f2bf(t0.w + p0.w) << 16);
      val.z = (u32)f2bf(t1.x + p1.x) | ((u32)f2bf(t1.y + p1.y) << 16);
      val.w = (u32)f2bf(t1.z + p1.z) | ((u32)f2bf(t1.w + p1.w) << 16);
    } else if (c0 == RW_NIN) {
      val.x = 0x3f803f80u;  // two bias nodes = bf16 1.0
    }
    vb4[(size_t)b * (RW_VBLD / 8) + j] = val;
  }
}

// scatter sparse weights into dense bf16 W^T[n][k]
__global__ __launch_bounds__(256) void rwnn_scatter(
    const uint32_t* __restrict__ pack, const float* __restrict__ w,
    unsigned short* __restrict__ wdt, GArgs ga, int Epad) {
  const int i = blockIdx.x * 256 + threadIdx.x;
  if (i >= Epad) return;
  int l = 0;
#pragma unroll
  for (int k = 1; k < RW_NLAYERS; ++k)
    if (i >= ga.p0[k]) l = k;
  const int kk = i - ga.p0[l];
  if (kk >= ga.er[l]) return;
  const uint32_t pk = pack[i];
  const unsigned u = pk & 4095u, v = pk >> 12;
  wdt[ga.wofs[l] + (size_t)v * (unsigned)ga.kpad[l] + u] =
      f2bf(w[ga.w0[l] + kk]);
}

// ---------------------------------------------------------------------------
// GEMM: pre[512,Npad] += Vb[512,K] * W^T[Npad,K]^T  (split-K, fp32 atomics)
// R6 structure + BK=64 + reg-prefetch double-buffer + chunk-XOR LDS swizzle.
// block = 4 waves; tile 128(M) x 32(N) x 64(K); wave tile 32x32.
// ---------------------------------------------------------------------------
__global__ __launch_bounds__(256) void rwnn_gemm(
    const unsigned short* __restrict__ Vb,
    const unsigned short* __restrict__ Bt, float* __restrict__ pre, int kpad,
    int ck) {
  __shared__ unsigned short As[128 * 64];  // 16 KB, row stride 128 B, swizzled
  __shared__ unsigned short Bs[32 * 64];   // 4 KB
  const int tid = threadIdx.x;
  const int wave = tid >> 6, lane = tid & 63;
  const int mt = blockIdx.x, nt = blockIdx.y, sk = blockIdx.z;
  const int k0 = sk * ck;
  const int k1 = min(k0 + ck, kpad);
  const int nit = (k1 - k0 + 63) >> 6;  // >=1 for all configured (sk,ck)

  // staging geometry (iteration-invariant): 256 threads cover
  // A: 128 rows x 8 chunks(16B) via j=0..3; B: 32 rows x 8 chunks exactly.
  const int arow = tid >> 3;                  // 0..31
  const int ach = tid & 7;                    // chunk 0..7
  const int aswz = (ach ^ (arow & 7)) << 4;   // swizzled byte offset in row
  const unsigned short* gA =
      Vb + (size_t)(mt * 128 + arow) * RW_VBLD + ach * 8;
  const unsigned short* gB = Bt + (size_t)(nt * 32 + arow) * kpad + ach * 8;
  float4 pfa0, pfa1, pfa2, pfa3, pfb;

#define LOADREGS(kk)                                                      \
  do {                                                                    \
    pfa0 = *(const float4*)(gA + (kk));                                   \
    pfa1 = *(const float4*)(gA + (size_t)32 * RW_VBLD + (kk));            \
    pfa2 = *(const float4*)(gA + (size_t)64 * RW_VBLD + (kk));            \
    pfa3 = *(const float4*)(gA + (size_t)96 * RW_VBLD + (kk));            \
    pfb = *(const float4*)(gB + (kk));                                    \
  } while (0)

  LOADREGS(k0);

  const int lr = lane & 15, gc4 = lane >> 4;
  f32x4 acc[2][2] = {};

  for (int t = 0; t < nit; ++t) {
    __syncthreads();  // previous tile's compute done; LDS reusable
    *(float4*)((char*)As + (arow)*128 + aswz) = pfa0;
    *(float4*)((char*)As + (32 + arow) * 128 + aswz) = pfa1;
    *(float4*)((char*)As + (64 + arow) * 128 + aswz) = pfa2;
    *(float4*)((char*)As + (96 + arow) * 128 + aswz) = pfa3;
    *(float4*)((char*)Bs + arow * 128 + aswz) = pfb;
    __syncthreads();  // tile ready
    if (t + 1 < nit) LOADREGS(k0 + (t + 1) * 64);  // prefetch: vmcnt pending
#pragma unroll
    for (int kk = 0; kk < 2; ++kk) {
      const int sa = ((kk * 4 + gc4) ^ (lr & 7)) << 4;
      const short8 a0 =
          *(const short8*)((char*)As + (wave * 32 + lr) * 128 + sa);
      const short8 a1 =
          *(const short8*)((char*)As + (wave * 32 + 16 + lr) * 128 + sa);
      const short8 b0 = *(const short8*)((char*)Bs + lr * 128 + sa);
      const short8 b1 = *(const short8*)((char*)Bs + (16 + lr) * 128 + sa);
      acc[0][0] =
          __builtin_amdgcn_mfma_f32_16x16x32_bf16(a0, b0, acc[0][0], 0, 0, 0);
      acc[0][1] =
          __builtin_amdgcn_mfma_f32_16x16x32_bf16(a0, b1, acc[0][1], 0, 0, 0);
      acc[1][0] =
          __builtin_amdgcn_mfma_f32_16x16x32_bf16(a1, b0, acc[1][0], 0, 0, 0);
      acc[1][1] =
          __builtin_amdgcn_mfma_f32_16x16x32_bf16(a1, b1, acc[1][1], 0, 0, 0);
    }
  }
#undef LOADREGS

  const int lq = lane >> 4;
#pragma unroll
  for (int ms = 0; ms < 2; ++ms)
#pragma unroll
    for (int ns = 0; ns < 2; ++ns)
#pragma unroll
      for (int r = 0; r < 4; ++r) {
        const int grow = mt * 128 + wave * 32 + ms * 16 + lq * 4 + r;
        const int gcol = nt * 32 + ns * 16 + lr;
        atomicAdd(pre + (size_t)grow * 512 + gcol, acc[ms][ns][r]);
      }
}

// per-layer epilogue: tanh(+bf16) into Vb (or fp32 logits to out); re-zero pre
__global__ __launch_bounds__(256) void rwnn_epi(
    float* __restrict__ pre, unsigned short* __restrict__ Vb,
    float* __restrict__ out, int start, int nsize, int last) {
  const int b = blockIdx.x;
  for (int n = threadIdx.x; n < 512; n += 256) {
    const float v = pre[(size_t)b * 512 + n];
    pre[(size_t)b * 512 + n] = 0.0f;
    if (n < nsize) {
      if (last)
        out[(size_t)b * 512 + n] = v;
      else
        Vb[(size_t)b * RW_VBLD + start + n] = f2bf(tanhf(v));
    }
  }
}

// ---------------------------------------------------------------------------
// Fallback (verified round-5 path) if ws_size too small for the dense plan
// ---------------------------------------------------------------------------
__global__ __launch_bounds__(256) void rwnn_build_w(const float* __restrict__ w,
                                                    float* __restrict__ wpad,
                                                    GArgs ga, int Epad) {
  const int i = blockIdx.x * 256 + threadIdx.x;
  if (i >= Epad) return;
  int l = 0;
#pragma unroll
  for (int k = 1; k < RW_NLAYERS; ++k)
    if (i >= ga.p0[k]) l = k;
  const int kk = i - ga.p0[l];
  wpad[i] = (kk < ga.er[l]) ? w[ga.w0[l] + kk] : 0.0f;
}

__global__ __launch_bounds__(512) void rwnn_fwd_sparse(
    const int* __restrict__ ids, const float* __restrict__ tok,
    const float* __restrict__ pos, const uint32_t* __restrict__ pack,
    const float* __restrict__ wpad, float* __restrict__ out, GArgs ga) {
  __shared__ float vals[4000];
  const int b = blockIdx.x;
  const int tid = threadIdx.x;
  for (int i = tid; i < RW_NIN; i += 512) {
    const int t = i >> 5, d = i & 31;
    vals[i] = tok[(ids[b * RW_T + t] << 5) + d] + pos[i];
  }
  if (tid < RW_NBIAS) vals[RW_NIN + tid] = 1.0f;
  const int sizes[RW_NLAYERS] = {288, 288, 288, 287, 287, 512};
  int nb = RW_NIN + RW_NBIAS;
  for (int li = 0; li < RW_NLAYERS; ++li) {
    const int size = sizes[li];
    __syncthreads();
    for (int v = tid; v < size; v += 512) vals[nb + v] = 0.0f;
    __syncthreads();
    const int p0 = ga.p0[li], ng = ga.ep[li] >> 2;
    for (int g = tid; g < ng; g += 512) {
      const int e = p0 + (g << 2);
      const uint4 pk = *reinterpret_cast<const uint4*>(pack + e);
      const float4 wv = *reinterpret_cast<const float4*>(wpad + e);
      atomicAdd(&vals[nb + (pk.x >> 12)], vals[pk.x & 4095u] * wv.x);
      atomicAdd(&vals[nb + (pk.y >> 12)], vals[pk.y & 4095u] * wv.y);
      atomicAdd(&vals[nb + (pk.z >> 12)], vals[pk.z & 4095u] * wv.z);
      atomicAdd(&vals[nb + (pk.w >> 12)], vals[pk.w & 4095u] * wv.w);
    }
    __syncthreads();
    if (li == RW_NLAYERS - 1) {
      for (int v = tid; v < RW_VOCAB; v += 512)
        out[b * RW_VOCAB + v] = vals[nb + v];
    } else {
      for (int v = tid; v < size; v += 512) vals[nb + v] = tanhf(vals[nb + v]);
    }
    nb += size;
  }
}

// ---------------------------------------------------------------------------
extern "C" void kernel_launch(void* const* d_in, const int* in_sizes, int n_in,
                              void* d_out, int out_size, void* d_ws,
                              size_t ws_size, hipStream_t stream) {
  static HostGraph* G = build_host_graph();
  const int Epad = G->Epad;

  const int* ids = (const int*)d_in[0];
  const float* tok = (const float*)d_in[1];
  const float* pos = (const float*)d_in[2];
  const float* w = (const float*)d_in[3];
  float* out = (float*)d_out;

  GArgs ga;
  memcpy(&ga, &G->ga, sizeof(GArgs));

  char* ws = (char*)d_ws;
  const size_t packB = ((size_t)Epad * 4 + 255) & ~(size_t)255;
  const size_t wdtB = ((size_t)G->wdt_elems * 2 + 255) & ~(size_t)255;
  const size_t vbB = (size_t)RW_BATCH * RW_VBLD * 2;  // 4 MB
  const size_t preB = (size_t)RW_BATCH * 512 * 4;     // 1 MB
  const size_t need = packB + wdtB + vbB + preB;

  uint32_t* d_pack = (uint32_t*)ws;
  hipMemcpyAsync(d_pack, G->h_pack, (size_t)Epad * 4, hipMemcpyHostToDevice,
                 stream);

  if (ws_size < need) {  // fallback: verified sparse path
    float* d_wpad = (float*)(ws + packB);
    rwnn_build_w<<<(Epad + 255) / 256, 256, 0, stream>>>(w, d_wpad, ga, Epad);
    rwnn_fwd_sparse<<<RW_BATCH, 512, 0, stream>>>(ids, tok, pos, d_pack,
                                                  d_wpad, out, ga);
    return;
  }

  unsigned short* d_wdt = (unsigned short*)(ws + packB);
  unsigned short* d_vb = (unsigned short*)(ws + packB + wdtB);
  float* d_pre = (float*)(ws + packB + wdtB + vbB);

  rwnn_init<<<1024, 256, 0, stream>>>((uint4*)d_wdt, (int)(G->wdt_elems / 8),
                                      (uint4*)d_pre, (uint4*)d_vb, ids, tok,
                                      pos);
  rwnn_scatter<<<(Epad + 255) / 256, 256, 0, stream>>>(d_pack, w, d_wdt, ga,
                                                       Epad);
  for (int l = 0; l < RW_NLAYERS; ++l) {
    const int SK = LAYER_SK[l];
    const int kpad = ga.kpad[l];
    const int ck = ((kpad + SK - 1) / SK + 63) & ~63;
    rwnn_gemm<<<dim3(4, LAYER_NT[l], SK), 256, 0, stream>>>(
        d_vb, d_wdt + ga.wofs[l], d_pre, kpad, ck);
    rwnn_epi<<<RW_BATCH, 256, 0, stream>>>(d_pre, d_vb, out, LAYER_START[l],
                                           LAYER_SIZES[l],
                                           l == RW_NLAYERS - 1 ? 1 : 0);
  }
}